// Round 1
// baseline (1337.783 us; speedup 1.0000x reference)
//
#include <hip/hip_runtime.h>

// NonLocalBlock: B=2, C=256, D*H*W=N=6272, mid=128.
// Round 0: correct fp32 flash-attention pipeline (no NxN materialization).
// Precision note: logits have std ~22 -> near-one-hot softmax; QK^T must be
// fp32-accurate (bf16 would swap near-tied argmax rows and blow the 2% abs
// threshold). PV/epilogue are bf16-tolerant (future MFMA rounds).

#define BB  2
#define CC  256
#define NN  6272
#define MID 128
#define TQ  64
#define TK  64

__device__ __forceinline__ void fma4(float4& a, const float4 v, const float s) {
    a.x += v.x * s; a.y += v.y * s; a.z += v.z * s; a.w += v.w * s;
}
__device__ __forceinline__ float dot4(const float4 a, const float4 b) {
    return a.x * b.x + a.y * b.y + a.z * b.z + a.w * b.w;
}

// ---------------------------------------------------------------------------
// Projection: e[pj][b][n][m] = dot(w_pj[m,:], x[b,:,n]) + bias_pj[m]
// grid (NN/64, 3, BB), block 256. LDS x-tile stride 68 (2-way banks).
// ---------------------------------------------------------------------------
__global__ __launch_bounds__(256, 2) void proj_kernel(
    const float* __restrict__ x,
    const float* __restrict__ w1, const float* __restrict__ bi1,
    const float* __restrict__ w2, const float* __restrict__ bi2,
    const float* __restrict__ w3, const float* __restrict__ bi3,
    float* __restrict__ eAll)
{
    const int t  = threadIdx.x;
    const int n0 = blockIdx.x * 64;
    const int pj = blockIdx.y;
    const int b  = blockIdx.z;
    const float* w  = (pj == 0) ? w1 : (pj == 1) ? w2 : w3;
    const float* bi = (pj == 0) ? bi1 : (pj == 1) ? bi2 : bi3;

    __shared__ float xs[CC * 68];
    {
        const float* xb = x + (size_t)b * CC * NN;
        for (int r = t; r < CC * 16; r += 256) {
            int c = r >> 4, j = (r & 15) << 2;
            float4 v = *(const float4*)(xb + (size_t)c * NN + n0 + j);
            *(float4*)&xs[c * 68 + j] = v;
        }
    }
    __syncthreads();

    const int n4 = (t & 15) << 2;   // 4 consecutive n per thread
    const int m0 = (t >> 4) << 3;   // 8 m-rows per thread
    float4 acc4[8];                 // acc4[k] = outputs over the 4 n's
    #pragma unroll
    for (int k = 0; k < 8; ++k) acc4[k] = make_float4(0.f, 0.f, 0.f, 0.f);

    for (int cc = 0; cc < CC; cc += 4) {
        float4 xv[4];
        #pragma unroll
        for (int u = 0; u < 4; ++u)
            xv[u] = *(const float4*)&xs[(cc + u) * 68 + n4];
        #pragma unroll
        for (int k = 0; k < 8; ++k) {
            float4 wq = *(const float4*)(w + (size_t)(m0 + k) * CC + cc);
            fma4(acc4[k], xv[0], wq.x);
            fma4(acc4[k], xv[1], wq.y);
            fma4(acc4[k], xv[2], wq.z);
            fma4(acc4[k], xv[3], wq.w);
        }
    }

    float4 bl0 = *(const float4*)(bi + m0);
    float4 bl1 = *(const float4*)(bi + m0 + 4);
    float* eo = eAll + ((size_t)(pj * BB + b)) * NN * MID;
    const float* af = (const float*)acc4;   // af[k*4 + i]
    #pragma unroll
    for (int i = 0; i < 4; ++i) {
        float4 r0, r1;
        r0.x = af[0 * 4 + i] + bl0.x;  r0.y = af[1 * 4 + i] + bl0.y;
        r0.z = af[2 * 4 + i] + bl0.z;  r0.w = af[3 * 4 + i] + bl0.w;
        r1.x = af[4 * 4 + i] + bl1.x;  r1.y = af[5 * 4 + i] + bl1.y;
        r1.z = af[6 * 4 + i] + bl1.z;  r1.w = af[7 * 4 + i] + bl1.w;
        float* row = eo + (size_t)(n0 + n4 + i) * MID + m0;
        *(float4*)(row)     = r0;
        *(float4*)(row + 4) = r1;
    }
}

// ---------------------------------------------------------------------------
// Flash attention, fp32. grid (NN/TQ, BB), block 256.
// K tile stored transposed [d][k] with XOR-swizzled k-groups:
//   addr(d,k) = d*64 + (((k>>2) ^ ((d>>2)&7))<<2) + (k&3)
// -> b128 reads along k are 2-way (free); staging writes ~4-way (rare).
// ---------------------------------------------------------------------------
__global__ __launch_bounds__(256, 1) void attn_kernel(
    const float* __restrict__ eAll, float* __restrict__ attnW)
{
    const int t  = threadIdx.x;
    const int n0 = blockIdx.x * TQ;
    const int b  = blockIdx.y;

    const float* Qg = eAll + ((size_t)(0 * BB + b)) * NN * MID;
    const float* Kg = eAll + ((size_t)(1 * BB + b)) * NN * MID;
    const float* Vg = eAll + ((size_t)(2 * BB + b)) * NN * MID;

    __shared__ float Qs[TQ * 132];     // padded: 2-way on 4-row-strided reads
    __shared__ float Ks[128 * 64];     // [d][k], swizzled
    __shared__ float Vs[TK * 128];     // [k][d]
    __shared__ float Ss[TQ * 65];      // odd stride: 2-way row/col access
    __shared__ float mS[TQ], lS[TQ], aS[TQ];
    __shared__ float red[4 * TQ];

    // stage Q once
    for (int r = t; r < TQ * 32; r += 256) {
        int q = r >> 5, g = r & 31;
        float4 v = *(const float4*)(Qg + (size_t)(n0 + q) * MID + (g << 2));
        *(float4*)&Qs[q * 132 + (g << 2)] = v;
    }
    if (t < TQ) { mS[t] = -3.0e38f; lS[t] = 0.f; }

    float4 o4[8];                       // O accumulator: 32 d's per thread
    #pragma unroll
    for (int jj = 0; jj < 8; ++jj) o4[jj] = make_float4(0.f, 0.f, 0.f, 0.f);

    const int ki4 = t & 15, qi4 = t >> 4;   // QK: 4q x 4k tile
    const int q0 = qi4 << 2, k0v = ki4 << 2;
    const int qo = t & 63, dg = t >> 6;     // PV: (query, d-chunk)

    __syncthreads();

    for (int kt = 0; kt < NN / TK; ++kt) {
        const int nk = kt * TK;
        // ---- stage K (transposed+swizzled) and V ----
        #pragma unroll
        for (int it = 0; it < 8; ++it) {
            int idx = it * 256 + t;
            int k = idx >> 5, g = idx & 31;
            float4 kvv = *(const float4*)(Kg + (size_t)(nk + k) * MID + (g << 2));
            int base = (g << 2) * 64 + ((((k >> 2) ^ (g & 7)) << 2) + (k & 3));
            Ks[base]       = kvv.x;
            Ks[base + 64]  = kvv.y;
            Ks[base + 128] = kvv.z;
            Ks[base + 192] = kvv.w;
            float4 vvv = *(const float4*)(Vg + (size_t)(nk + k) * MID + (g << 2));
            *(float4*)&Vs[k * 128 + (g << 2)] = vvv;
        }
        __syncthreads();

        // ---- QK^T: per-thread 4x4 scores over K=128 ----
        float4 sacc[4];
        #pragma unroll
        for (int i = 0; i < 4; ++i) sacc[i] = make_float4(0.f, 0.f, 0.f, 0.f);
        #pragma unroll 4
        for (int ds = 0; ds < 32; ++ds) {
            float4 qv[4], kv[4];
            #pragma unroll
            for (int i = 0; i < 4; ++i)
                qv[i] = *(const float4*)&Qs[(q0 + i) * 132 + (ds << 2)];
            const int koff = (ki4 ^ (ds & 7)) << 2;
            #pragma unroll
            for (int u = 0; u < 4; ++u)
                kv[u] = *(const float4*)&Ks[((ds << 2) + u) * 64 + koff];
            #pragma unroll
            for (int i = 0; i < 4; ++i) {
                fma4(sacc[i], kv[0], qv[i].x);
                fma4(sacc[i], kv[1], qv[i].y);
                fma4(sacc[i], kv[2], qv[i].z);
                fma4(sacc[i], kv[3], qv[i].w);
            }
        }
        #pragma unroll
        for (int i = 0; i < 4; ++i) {
            float* sp = &Ss[(q0 + i) * 65 + k0v];
            sp[0] = sacc[i].x; sp[1] = sacc[i].y;
            sp[2] = sacc[i].z; sp[3] = sacc[i].w;
        }
        __syncthreads();

        // ---- online softmax: partial max ----
        {
            const int q = t & 63, seg = t >> 6;
            const float* sr = &Ss[q * 65 + seg * 16];
            float mx = -3.0e38f;
            #pragma unroll
            for (int j = 0; j < 16; ++j) mx = fmaxf(mx, sr[j]);
            red[seg * 64 + q] = mx;
        }
        __syncthreads();
        if (t < TQ) {
            float m_new = fmaxf(mS[t],
                fmaxf(fmaxf(red[t], red[64 + t]), fmaxf(red[128 + t], red[192 + t])));
            aS[t] = __expf(mS[t] - m_new);
            mS[t] = m_new;
        }
        __syncthreads();
        // ---- exp + partial sum (p written back into Ss) ----
        {
            const int q = t & 63, seg = t >> 6;
            float* sr = &Ss[q * 65 + seg * 16];
            const float mrow = mS[q];
            float s = 0.f;
            #pragma unroll
            for (int j = 0; j < 16; ++j) {
                float p = __expf(sr[j] - mrow);
                sr[j] = p;
                s += p;
            }
            red[seg * 64 + q] = s;
        }
        __syncthreads();
        if (t < TQ)
            lS[t] = lS[t] * aS[t] + (red[t] + red[64 + t] + red[128 + t] + red[192 + t]);

        // ---- PV: o = o*alpha + P @ V (V reads are full-wave broadcast) ----
        {
            const float al = aS[qo];
            #pragma unroll
            for (int jj = 0; jj < 8; ++jj) {
                o4[jj].x *= al; o4[jj].y *= al; o4[jj].z *= al; o4[jj].w *= al;
            }
            const float* pr = &Ss[qo * 65];
            const float* vb = &Vs[dg * 32];
            #pragma unroll 2
            for (int k = 0; k < TK; ++k) {
                const float pv = pr[k];
                #pragma unroll
                for (int jj = 0; jj < 8; ++jj) {
                    float4 vv = *(const float4*)(vb + k * 128 + (jj << 2));
                    fma4(o4[jj], vv, pv);
                }
            }
        }
        __syncthreads();
    }

    // ---- normalize + store attn[b][n][m] ----
    {
        const float inv = 1.0f / lS[qo];
        float* op = attnW + ((size_t)b * NN + (n0 + qo)) * MID + dg * 32;
        #pragma unroll
        for (int jj = 0; jj < 8; ++jj) {
            float4 r = o4[jj];
            r.x *= inv; r.y *= inv; r.z *= inv; r.w *= inv;
            *(float4*)(op + (jj << 2)) = r;
        }
    }
}

// ---------------------------------------------------------------------------
// Epilogue: out[b][c][n] = x + w4 @ attn^T + b4. grid (NN/64, BB), block 256.
// ---------------------------------------------------------------------------
__global__ __launch_bounds__(256, 2) void epi_kernel(
    const float* __restrict__ attnW, const float* __restrict__ w4,
    const float* __restrict__ b4, const float* __restrict__ x,
    float* __restrict__ out)
{
    const int t  = threadIdx.x;
    const int n0 = blockIdx.x * 64;
    const int b  = blockIdx.y;

    __shared__ float as[64 * 132];
    for (int r = t; r < 64 * 32; r += 256) {
        int q = r >> 5, g = r & 31;
        float4 v = *(const float4*)(attnW + ((size_t)b * NN + (n0 + q)) * MID + (g << 2));
        *(float4*)&as[q * 132 + (g << 2)] = v;
    }
    __syncthreads();

    const int n4 = (t & 15) << 2;   // 4 n's
    const int c0 = (t >> 4) << 4;   // 16 c's
    float4 accE[16];                // accE[k] over the 4 n's
    #pragma unroll
    for (int k = 0; k < 16; ++k) accE[k] = make_float4(0.f, 0.f, 0.f, 0.f);

    for (int ms = 0; ms < 32; ++ms) {
        float4 av[4];
        #pragma unroll
        for (int i = 0; i < 4; ++i)
            av[i] = *(const float4*)&as[(n4 + i) * 132 + (ms << 2)];
        #pragma unroll
        for (int k = 0; k < 16; ++k) {
            float4 wq = *(const float4*)(w4 + (size_t)(c0 + k) * MID + (ms << 2));
            accE[k].x += dot4(av[0], wq);
            accE[k].y += dot4(av[1], wq);
            accE[k].z += dot4(av[2], wq);
            accE[k].w += dot4(av[3], wq);
        }
    }

    #pragma unroll
    for (int k = 0; k < 16; ++k) {
        const int c = c0 + k;
        const float bv = b4[c];
        const size_t off = ((size_t)b * CC + c) * NN + n0 + n4;
        float4 xr = *(const float4*)(x + off);
        float4 r;
        r.x = accE[k].x + bv + xr.x;
        r.y = accE[k].y + bv + xr.y;
        r.z = accE[k].z + bv + xr.z;
        r.w = accE[k].w + bv + xr.w;
        *(float4*)(out + off) = r;
    }
}

extern "C" void kernel_launch(void* const* d_in, const int* in_sizes, int n_in,
                              void* d_out, int out_size, void* d_ws, size_t ws_size,
                              hipStream_t stream)
{
    const float* x  = (const float*)d_in[0];
    const float* w1 = (const float*)d_in[1];
    const float* b1 = (const float*)d_in[2];
    const float* w2 = (const float*)d_in[3];
    const float* b2 = (const float*)d_in[4];
    const float* w3 = (const float*)d_in[5];
    const float* b3 = (const float*)d_in[6];
    const float* w4 = (const float*)d_in[7];
    const float* b4 = (const float*)d_in[8];
    float* out = (float*)d_out;

    // ws layout: eAll[3][B][N][128] then attn[B][N][128]  (24.5 MiB total)
    float* eAll  = (float*)d_ws;
    float* attnW = eAll + (size_t)3 * BB * NN * MID;

    proj_kernel<<<dim3(NN / 64, 3, BB), 256, 0, stream>>>(x, w1, b1, w2, b2, w3, b3, eAll);
    attn_kernel<<<dim3(NN / TQ, BB), 256, 0, stream>>>(eAll, attnW);
    epi_kernel<<<dim3(NN / 64, BB), 256, 0, stream>>>(attnW, w4, b4, x, out);
}

// Round 2
// 306.511 us; speedup vs baseline: 4.3646x; 4.3646x over previous
//
#include <hip/hip_runtime.h>

// NonLocalBlock: B=2, C=256, N=D*H*W=6272, mid=128.
// R1: f16-MFMA flash attention (S^T = K.Q^T, O^T = V^T.P^T), fp32 accumulate.
// Q-frags pinned in registers; per-block TQ=32 q-rows, 2 waves split k'-halves
// with independent online-softmax state, merged once at the end (flash-decode
// within block). LDS exactly 40 KB -> 4 blocks/CU. proj emits f16 Q,K ([n][d])
// and f16 V^T ([d][n]); epi stays fp32 vector.

#define BB  2
#define CC  256
#define NN  6272
#define MID 128

typedef _Float16 half4_t __attribute__((ext_vector_type(4)));
typedef _Float16 half8_t __attribute__((ext_vector_type(8)));
typedef float    floatx16 __attribute__((ext_vector_type(16)));

__device__ __forceinline__ void fma4(float4& a, const float4 v, const float s) {
    a.x += v.x * s; a.y += v.y * s; a.z += v.z * s; a.w += v.w * s;
}
__device__ __forceinline__ float dot4(const float4 a, const float4 b) {
    return a.x * b.x + a.y * b.y + a.z * b.z + a.w * b.w;
}

// ---------------------------------------------------------------------------
// Projection: e_pj[n][m] = dot(w_pj[m,:], x[b,:,n]) + bias.
// pj 0 -> Qg f16 [b][n][128]; pj 1 -> Kg f16 [b][n][128]; pj 2 -> VtG f16 [b][128][n].
// grid (NN/64, 3, BB), block 256.
// ---------------------------------------------------------------------------
__global__ __launch_bounds__(256, 2) void proj_kernel(
    const float* __restrict__ x,
    const float* __restrict__ w1, const float* __restrict__ bi1,
    const float* __restrict__ w2, const float* __restrict__ bi2,
    const float* __restrict__ w3, const float* __restrict__ bi3,
    _Float16* __restrict__ Qg, _Float16* __restrict__ Kg, _Float16* __restrict__ VtG)
{
    const int t  = threadIdx.x;
    const int n0 = blockIdx.x * 64;
    const int pj = blockIdx.y;
    const int b  = blockIdx.z;
    const float* w  = (pj == 0) ? w1 : (pj == 1) ? w2 : w3;
    const float* bi = (pj == 0) ? bi1 : (pj == 1) ? bi2 : bi3;

    __shared__ float xs[CC * 68];
    {
        const float* xb = x + (size_t)b * CC * NN;
        for (int r = t; r < CC * 16; r += 256) {
            int c = r >> 4, j = (r & 15) << 2;
            float4 v = *(const float4*)(xb + (size_t)c * NN + n0 + j);
            *(float4*)&xs[c * 68 + j] = v;
        }
    }
    __syncthreads();

    const int n4 = (t & 15) << 2;   // 4 consecutive n per thread
    const int m0 = (t >> 4) << 3;   // 8 m-rows per thread
    float4 acc4[8];
    #pragma unroll
    for (int k = 0; k < 8; ++k) acc4[k] = make_float4(0.f, 0.f, 0.f, 0.f);

    for (int cc = 0; cc < CC; cc += 4) {
        float4 xv[4];
        #pragma unroll
        for (int u = 0; u < 4; ++u)
            xv[u] = *(const float4*)&xs[(cc + u) * 68 + n4];
        #pragma unroll
        for (int k = 0; k < 8; ++k) {
            float4 wq = *(const float4*)(w + (size_t)(m0 + k) * CC + cc);
            fma4(acc4[k], xv[0], wq.x);
            fma4(acc4[k], xv[1], wq.y);
            fma4(acc4[k], xv[2], wq.z);
            fma4(acc4[k], xv[3], wq.w);
        }
    }

    const float* af = (const float*)acc4;   // af[k*4 + i], i = n-sub, k = m-sub
    float bb[8];
    #pragma unroll
    for (int k = 0; k < 8; ++k) bb[k] = bi[m0 + k];

    if (pj < 2) {
        _Float16* eo = ((pj == 0) ? Qg : Kg) + (size_t)b * NN * MID;
        #pragma unroll
        for (int i = 0; i < 4; ++i) {
            half8_t h;
            #pragma unroll
            for (int k = 0; k < 8; ++k) h[k] = (_Float16)(af[k * 4 + i] + bb[k]);
            *(half8_t*)(eo + (size_t)(n0 + n4 + i) * MID + m0) = h;
        }
    } else {
        _Float16* eo = VtG + (size_t)b * MID * NN;
        #pragma unroll
        for (int k = 0; k < 8; ++k) {
            half4_t h;
            #pragma unroll
            for (int i = 0; i < 4; ++i) h[i] = (_Float16)(af[k * 4 + i] + bb[k]);
            *(half4_t*)(eo + (size_t)(m0 + k) * NN + n0 + n4) = h;
        }
    }
}

// ---------------------------------------------------------------------------
// Flash attention, f16 MFMA. grid (NN/32, BB), block 128 (2 waves).
// Wave w owns k'-half w of each 64-key tile; independent (m,l,O); end merge.
// S^T tile: D[k'][q]: col q = lane&31, row k' = (reg&3)+8*(reg>>2)+4*(lane>>5).
// LDS layout (40960 B total):
//   Ks  [64][136] f16  (17408 B)   A-operand of S^T = K.Q^T
//   Vt  [128][72] f16  (18432 B)   A-operand of O^T = V^T.P^T
//   Pt  [32][72]  f16  ( 4608 B)   B-operand (P^T), written from S^T regs
//   stats 128 f32      (  512 B)
//   Obuf [32][132] f32 aliases Ks for the end merge.
// ---------------------------------------------------------------------------
__global__ __launch_bounds__(128, 2) void attn_kernel(
    const _Float16* __restrict__ Qg, const _Float16* __restrict__ Kg,
    const _Float16* __restrict__ VtG, float* __restrict__ attnW)
{
    const int t    = threadIdx.x;
    const int lane = t & 63;
    const int wave = t >> 6;        // k'-half
    const int l31  = lane & 31;
    const int l5   = lane >> 5;
    const int q0   = blockIdx.x * 32;
    const int b    = blockIdx.y;

    __shared__ __align__(16) char lds[40960];
    _Float16* Ks = (_Float16*)lds;                       // 64*136 halfs
    _Float16* Vt = (_Float16*)(lds + 17408);             // 128*72 halfs
    _Float16* Pt = (_Float16*)(lds + 17408 + 18432);     // 32*72 halfs
    float* stats = (float*)(lds + 40448);                // 128 f32
    float* Obuf  = (float*)lds;                          // 32*132 f32 (alias Ks)

    const _Float16* Qb = Qg + ((size_t)b * NN + q0) * MID;
    const _Float16* Kb = Kg + (size_t)b * NN * MID;
    const _Float16* Vb = VtG + (size_t)b * MID * NN;

    // Q B-frags: loop-invariant, pinned in registers.
    // B[k=d][n=q]: lane holds Q[q0+l31][ds*16 + l5*8 + j]
    half8_t qf[8];
    #pragma unroll
    for (int ds = 0; ds < 8; ++ds)
        qf[ds] = *(const half8_t*)(Qb + (size_t)l31 * MID + ds * 16 + l5 * 8);

    floatx16 o[4];
    #pragma unroll
    for (int dt = 0; dt < 4; ++dt)
        #pragma unroll
        for (int j = 0; j < 16; ++j) o[dt][j] = 0.f;
    float m_run = -3.0e38f, l_run = 0.f;

    for (int kt = 0; kt < NN / 64; ++kt) {
        const int nk = kt * 64;
        // ---- stage K tile [64][136] and V^T tile [128][72] ----
        #pragma unroll
        for (int it = 0; it < 8; ++it) {
            int c = it * 128 + t;
            int r = c >> 4, off = (c & 15) * 8;
            *(half8_t*)(Ks + r * 136 + off) =
                *(const half8_t*)(Kb + (size_t)(nk + r) * MID + off);
        }
        #pragma unroll
        for (int it = 0; it < 8; ++it) {
            int c = it * 128 + t;
            int d = c >> 3, off = (c & 7) * 8;
            *(half8_t*)(Vt + d * 72 + off) =
                *(const half8_t*)(Vb + (size_t)d * NN + nk + off);
        }
        __syncthreads();

        // ---- S^T = K . Q^T over the wave's 32-k' strip ----
        floatx16 s;
        #pragma unroll
        for (int j = 0; j < 16; ++j) s[j] = 0.f;
        const _Float16* krow = Ks + (wave * 32 + l31) * 136 + l5 * 8;
        #pragma unroll
        for (int ds = 0; ds < 8; ++ds)
            s = __builtin_amdgcn_mfma_f32_32x32x16_f16(
                    *(const half8_t*)(krow + ds * 16), qf[ds], s, 0, 0, 0);

        // ---- online softmax (per lane: one q column, 16 of 32 k' rows) ----
        float tmax = s[0];
        #pragma unroll
        for (int j = 1; j < 16; ++j) tmax = fmaxf(tmax, s[j]);
        tmax = fmaxf(tmax, __shfl_xor(tmax, 32));
        const float m_new = fmaxf(m_run, tmax);
        const float alpha = __expf(m_run - m_new);
        m_run = m_new;

        float psum = 0.f;
        _Float16* prow = Pt + l31 * 72 + wave * 32 + 4 * l5;
        #pragma unroll
        for (int g = 0; g < 4; ++g) {
            float p0 = __expf(s[4 * g + 0] - m_new);
            float p1 = __expf(s[4 * g + 1] - m_new);
            float p2 = __expf(s[4 * g + 2] - m_new);
            float p3 = __expf(s[4 * g + 3] - m_new);
            psum += (p0 + p1) + (p2 + p3);
            half4_t h;
            h[0] = (_Float16)p0; h[1] = (_Float16)p1;
            h[2] = (_Float16)p2; h[3] = (_Float16)p3;
            *(half4_t*)(prow + 8 * g) = h;   // k' = wave*32 + 8g + 4*l5 + {0..3}
        }
        psum += __shfl_xor(psum, 32);
        l_run = l_run * alpha + psum;

        #pragma unroll
        for (int dt = 0; dt < 4; ++dt)
            #pragma unroll
            for (int j = 0; j < 16; ++j) o[dt][j] *= alpha;

        // Own-wave cross-lane LDS dependency (lane l reads lane l^32's Pt
        // writes): drain lgkmcnt, no block barrier needed (quadrants disjoint).
        __builtin_amdgcn_s_waitcnt(0xC07F);

        // ---- O^T += V^T . P^T over the wave's 32-kk strip ----
        #pragma unroll
        for (int ks = 0; ks < 2; ++ks) {
            half8_t pf = *(const half8_t*)(Pt + l31 * 72 + wave * 32 + ks * 16 + l5 * 8);
            const _Float16* vcol = Vt + wave * 32 + ks * 16 + l5 * 8;
            #pragma unroll
            for (int dt = 0; dt < 4; ++dt)
                o[dt] = __builtin_amdgcn_mfma_f32_32x32x16_f16(
                            *(const half8_t*)(vcol + (dt * 32 + l31) * 72), pf,
                            o[dt], 0, 0, 0);
        }
        __syncthreads();
    }

    // ---- merge the two k'-half partials, normalize, store ----
    if (l5 == 0) {
        stats[wave * 64 + l31]      = m_run;
        stats[wave * 64 + 32 + l31] = l_run;
    }
    __syncthreads();
    const float m_o  = stats[(1 ^ wave) * 64 + l31];
    const float l_o  = stats[(1 ^ wave) * 64 + 32 + l31];
    const float m_st = fmaxf(m_run, m_o);
    const float sc   = __expf(m_run - m_st);
    const float l_st = l_run * sc + l_o * __expf(m_o - m_st);
    const float inv  = 1.0f / l_st;

    if (wave == 1) {
        #pragma unroll
        for (int dt = 0; dt < 4; ++dt)
            #pragma unroll
            for (int j = 0; j < 16; ++j) {
                int d = dt * 32 + (j & 3) + 8 * (j >> 2) + 4 * l5;
                Obuf[l31 * 132 + d] = o[dt][j] * sc;
            }
    }
    __syncthreads();
    if (wave == 0) {
        #pragma unroll
        for (int dt = 0; dt < 4; ++dt)
            #pragma unroll
            for (int j = 0; j < 16; ++j) {
                int d = dt * 32 + (j & 3) + 8 * (j >> 2) + 4 * l5;
                Obuf[l31 * 132 + d] = (Obuf[l31 * 132 + d] + o[dt][j] * sc) * inv;
            }
    }
    __syncthreads();
    #pragma unroll
    for (int it = 0; it < 8; ++it) {
        int c = it * 128 + t;
        int q = c >> 5, off = (c & 31) * 4;
        *(float4*)(attnW + ((size_t)b * NN + q0 + q) * MID + off) =
            *(const float4*)(Obuf + q * 132 + off);
    }
}

// ---------------------------------------------------------------------------
// Epilogue: out[b][c][n] = x + w4 @ attn^T + b4. grid (NN/64, BB), block 256.
// ---------------------------------------------------------------------------
__global__ __launch_bounds__(256, 2) void epi_kernel(
    const float* __restrict__ attnW, const float* __restrict__ w4,
    const float* __restrict__ b4, const float* __restrict__ x,
    float* __restrict__ out)
{
    const int t  = threadIdx.x;
    const int n0 = blockIdx.x * 64;
    const int b  = blockIdx.y;

    __shared__ float as[64 * 132];
    for (int r = t; r < 64 * 32; r += 256) {
        int q = r >> 5, g = r & 31;
        float4 v = *(const float4*)(attnW + ((size_t)b * NN + (n0 + q)) * MID + (g << 2));
        *(float4*)&as[q * 132 + (g << 2)] = v;
    }
    __syncthreads();

    const int n4 = (t & 15) << 2;
    const int c0 = (t >> 4) << 4;
    float4 accE[16];
    #pragma unroll
    for (int k = 0; k < 16; ++k) accE[k] = make_float4(0.f, 0.f, 0.f, 0.f);

    for (int ms = 0; ms < 32; ++ms) {
        float4 av[4];
        #pragma unroll
        for (int i = 0; i < 4; ++i)
            av[i] = *(const float4*)&as[(n4 + i) * 132 + (ms << 2)];
        #pragma unroll
        for (int k = 0; k < 16; ++k) {
            float4 wq = *(const float4*)(w4 + (size_t)(c0 + k) * MID + (ms << 2));
            accE[k].x += dot4(av[0], wq);
            accE[k].y += dot4(av[1], wq);
            accE[k].z += dot4(av[2], wq);
            accE[k].w += dot4(av[3], wq);
        }
    }

    #pragma unroll
    for (int k = 0; k < 16; ++k) {
        const int c = c0 + k;
        const float bv = b4[c];
        const size_t off = ((size_t)b * CC + c) * NN + n0 + n4;
        float4 xr = *(const float4*)(x + off);
        float4 r;
        r.x = accE[k].x + bv + xr.x;
        r.y = accE[k].y + bv + xr.y;
        r.z = accE[k].z + bv + xr.z;
        r.w = accE[k].w + bv + xr.w;
        *(float4*)(out + off) = r;
    }
}

extern "C" void kernel_launch(void* const* d_in, const int* in_sizes, int n_in,
                              void* d_out, int out_size, void* d_ws, size_t ws_size,
                              hipStream_t stream)
{
    const float* x  = (const float*)d_in[0];
    const float* w1 = (const float*)d_in[1];
    const float* b1 = (const float*)d_in[2];
    const float* w2 = (const float*)d_in[3];
    const float* b2 = (const float*)d_in[4];
    const float* w3 = (const float*)d_in[5];
    const float* b3 = (const float*)d_in[6];
    const float* w4 = (const float*)d_in[7];
    const float* b4 = (const float*)d_in[8];
    float* out = (float*)d_out;

    // ws: Qg f16 [B][N][128] | Kg f16 [B][N][128] | VtG f16 [B][128][N] | attnW f32 [B][N][128]
    _Float16* Qg  = (_Float16*)d_ws;
    _Float16* Kg  = Qg + (size_t)BB * NN * MID;
    _Float16* VtG = Kg + (size_t)BB * NN * MID;
    float* attnW  = (float*)(VtG + (size_t)BB * NN * MID);

    proj_kernel<<<dim3(NN / 64, 3, BB), 256, 0, stream>>>(x, w1, b1, w2, b2, w3, b3, Qg, Kg, VtG);
    attn_kernel<<<dim3(NN / 32, BB), 128, 0, stream>>>(Qg, Kg, VtG, attnW);
    epi_kernel<<<dim3(NN / 64, BB), 256, 0, stream>>>(attnW, w4, b4, x, out);
}